// Round 1
// baseline (1010.248 us; speedup 1.0000x reference)
//
#include <hip/hip_runtime.h>

typedef unsigned short u16;
typedef __bf16 bf16x8 __attribute__((ext_vector_type(8)));
typedef float f32x4 __attribute__((ext_vector_type(4)));

__device__ __forceinline__ u16 f2bf(float f) {
  unsigned int u = __float_as_uint(f);
  u += 0x7fffu + ((u >> 16) & 1u);
  return (u16)(u >> 16);
}
__device__ __forceinline__ float bf2f(u16 v) {
  return __uint_as_float(((unsigned int)v) << 16);
}

// async global->LDS, 16B per lane. LDS dest must be wave-uniform base; HW adds lane*16.
__device__ __forceinline__ void gl_lds16(const u16* g, u16* l) {
  auto* lp = reinterpret_cast<__attribute__((address_space(3))) unsigned int*>(
      reinterpret_cast<uintptr_t>(l));
  auto* gp = reinterpret_cast<const __attribute__((address_space(1))) unsigned int*>(
      reinterpret_cast<uintptr_t>(g));
  __builtin_amdgcn_global_load_lds(gp, lp, 16, 0, 0);
}

// ---------------- fp32 -> bf16 convert ----------------
__global__ __launch_bounds__(256) void cvt_kernel(const float* __restrict__ in,
                                                  u16* __restrict__ out, int n4) {
  int i = blockIdx.x * 256 + threadIdx.x;
  if (i >= n4) return;
  float4 v = ((const float4*)in)[i];
  ushort4 o;
  o.x = f2bf(v.x); o.y = f2bf(v.y); o.z = f2bf(v.z); o.w = f2bf(v.w);
  ((ushort4*)out)[i] = o;
}

// ---------------- bf16 GEMM, C[m][n] = sum_k A[m][k] * B[n][k] ----------------
// 128x128 tile, BK=32, 256 threads (4 waves, 2x2 wave grid, 64x64 per wave).
template <int OUT_BF16>
__global__ __launch_bounds__(256) void gemm_bt(const u16* __restrict__ A,
                                               const u16* __restrict__ B,
                                               void* __restrict__ Cv, int M, int N, int K) {
  __shared__ u16 As[128 * 32];
  __shared__ u16 Bs[128 * 32];
  const int t = threadIdx.x;
  const int lane = t & 63, w = t >> 6;
  const int col = lane & 15, quad = lane >> 4;
  const int m0 = blockIdx.y * 128, n0 = blockIdx.x * 128;

  f32x4 acc[4][4] = {};

  const int r4 = t >> 2;          // 0..63
  const int c8 = (t & 3) * 8;     // k chunk within BK=32
  const u16* gA0 = A + (size_t)(m0 + r4) * K + c8;
  const u16* gA1 = A + (size_t)(m0 + 64 + r4) * K + c8;
  const u16* gB0 = B + (size_t)(n0 + r4) * K + c8;
  const u16* gB1 = B + (size_t)(n0 + 64 + r4) * K + c8;
  u16* lA0 = As + w * 512;        // wave-uniform LDS bases
  u16* lA1 = As + 2048 + w * 512;
  u16* lB0 = Bs + w * 512;
  u16* lB1 = Bs + 2048 + w * 512;

  const int mr = (w & 1) * 64, nr = (w >> 1) * 64;

  for (int k0 = 0; k0 < K; k0 += 32) {
    __syncthreads();
    gl_lds16(gA0 + k0, lA0);
    gl_lds16(gA1 + k0, lA1);
    gl_lds16(gB0 + k0, lB0);
    gl_lds16(gB1 + k0, lB1);
    __syncthreads();  // compiler drains vmcnt before s_barrier

    bf16x8 a[4], b[4];
#pragma unroll
    for (int i = 0; i < 4; i++)
      a[i] = *(const bf16x8*)&As[(mr + i * 16 + col) * 32 + quad * 8];
#pragma unroll
    for (int i = 0; i < 4; i++)
      b[i] = *(const bf16x8*)&Bs[(nr + i * 16 + col) * 32 + quad * 8];
#pragma unroll
    for (int i = 0; i < 4; i++)
#pragma unroll
      for (int j = 0; j < 4; j++)
        acc[i][j] = __builtin_amdgcn_mfma_f32_16x16x32_bf16(a[i], b[j], acc[i][j], 0, 0, 0);
  }

  // C/D layout: col = lane&15, row = quad*4 + reg
#pragma unroll
  for (int i = 0; i < 4; i++) {
#pragma unroll
    for (int j = 0; j < 4; j++) {
      int mb = m0 + mr + i * 16 + quad * 4;
      int n = n0 + nr + j * 16 + col;
#pragma unroll
      for (int r = 0; r < 4; r++) {
        float v = acc[i][j][r];
        if constexpr (OUT_BF16)
          ((u16*)Cv)[(size_t)(mb + r) * N + n] = f2bf(v);
        else
          ((float*)Cv)[(size_t)(mb + r) * N + n] = v;
      }
    }
  }
}

// ---------------- Llama-3.1 RoPE (rotate-half, non-interleaved) ----------------
__global__ __launch_bounds__(256) void rope_kernel(u16* __restrict__ X,
                                                   const int* __restrict__ pos_ids,
                                                   int log2H, int row_stride) {
  int tid = blockIdx.x * 256 + threadIdx.x;
  int i = tid & 63;
  int rest = tid >> 6;
  int h = rest & ((1 << log2H) - 1);
  int token = rest >> log2H;
  float pos = (float)pos_ids[token];
  // freq = 500000^(-i/64); log2(500000) = 18.93156856932417
  float fr = __builtin_exp2f(-(float)i * (18.93156856932417f / 64.0f));
  float wl = 6.283185307179586f / fr;
  float f2;
  if (wl < 2048.0f) f2 = fr;
  else if (wl > 8192.0f) f2 = fr * 0.125f;
  else {
    float sm = (8192.0f / wl - 1.0f) * (1.0f / 3.0f);
    f2 = (1.0f - sm) * fr * 0.125f + sm * fr;
  }
  float ang = pos * f2;
  float ss = sinf(ang), cc = cosf(ang);
  size_t base = (size_t)token * row_stride + (size_t)h * 128 + i;
  float x1 = bf2f(X[base]), x2 = bf2f(X[base + 64]);
  X[base] = f2bf(x1 * cc - x2 * ss);
  X[base + 64] = f2bf(x2 * cc + x1 * ss);
}

// ---------------- causal GQA flash attention ----------------
// grid (qt=16, h=32, b=4), 256 threads. BM=BN=64; wave w owns Q rows [w*16, w*16+16).
__global__ __launch_bounds__(256) void attn_kernel(const u16* __restrict__ Qg,
                                                   const u16* __restrict__ Kg,
                                                   const u16* __restrict__ Vg,
                                                   u16* __restrict__ Og) {
  const int qt = blockIdx.x, h = blockIdx.y, b = blockIdx.z;
  const int kvh = h >> 2;  // GQA group of 4
  const int t = threadIdx.x, lane = t & 63, w = t >> 6;
  const int col = lane & 15, quad = lane >> 4;

  __shared__ u16 Qs[64][136];      // padded rows (272B = 17*16)
  __shared__ u16 Ks[64][136];
  __shared__ u16 Vt[128][72];      // V transposed: [d][key], rows 144B
  __shared__ u16 Ps[4][16][72];    // per-wave P strip

  const int r = t >> 2, sg = t & 3;
  {
    const size_t qbase = (size_t)(b * 1024 + qt * 64 + r) * 4096 + h * 128;
#pragma unroll
    for (int ii = 0; ii < 4; ii++) {
      int d = (sg * 4 + ii) * 8;
      *(uint4*)&Qs[r][d] = *(const uint4*)&Qg[qbase + d];
    }
  }
  // Q staging is wave-local (thread t writes rows 16w..16w+15); same-wave LDS is in-order.
  bf16x8 qa[4];
#pragma unroll
  for (int kk = 0; kk < 4; kk++)
    qa[kk] = *(const bf16x8*)&Qs[w * 16 + col][quad * 8 + kk * 32];

  f32x4 o[8] = {};
  float m_i[4] = {-3.0e38f, -3.0e38f, -3.0e38f, -3.0e38f};
  float l_i[4] = {};

  const float cf = 0.08838834764831845f * 1.4426950408889634f;  // scale * log2(e)
  const int qrow0 = qt * 64 + w * 16 + quad * 4;

  for (int j = 0; j <= qt; j++) {
    __syncthreads();
    {
      const size_t kb = (size_t)(b * 1024 + j * 64 + r) * 2048 + kvh * 128;
#pragma unroll
      for (int ii = 0; ii < 4; ii++) {
        int d = (sg * 4 + ii) * 8;
        *(uint4*)&Ks[r][d] = *(const uint4*)&Kg[kb + d];
        uint4 vv = *(const uint4*)&Vg[kb + d];
        const u16* pv = (const u16*)&vv;
#pragma unroll
        for (int u = 0; u < 8; u++) Vt[d + u][r] = pv[u];
      }
    }
    __syncthreads();

    // S = Q K^T  (rows=q via A, cols=key via B)
    f32x4 s[4] = {};
#pragma unroll
    for (int nb = 0; nb < 4; nb++)
#pragma unroll
      for (int kk = 0; kk < 4; kk++) {
        bf16x8 kb2 = *(const bf16x8*)&Ks[nb * 16 + col][quad * 8 + kk * 32];
        s[nb] = __builtin_amdgcn_mfma_f32_16x16x32_bf16(qa[kk], kb2, s[nb], 0, 0, 0);
      }

    if (j == qt) {  // diagonal tile: causal mask
#pragma unroll
      for (int nb = 0; nb < 4; nb++)
#pragma unroll
        for (int rr = 0; rr < 4; rr++)
          if (j * 64 + nb * 16 + col > qrow0 + rr) s[nb][rr] = -3.0e38f;
    }

    // online softmax; rows live across the 16 lanes of each quad
    float mnew[4];
#pragma unroll
    for (int rr = 0; rr < 4; rr++) {
      mnew[rr] = m_i[rr];
#pragma unroll
      for (int nb = 0; nb < 4; nb++) mnew[rr] = fmaxf(mnew[rr], s[nb][rr]);
    }
#pragma unroll
    for (int off = 1; off < 16; off <<= 1)
#pragma unroll
      for (int rr = 0; rr < 4; rr++)
        mnew[rr] = fmaxf(mnew[rr], __shfl_xor(mnew[rr], off));

    float p[4][4], rs[4], alpha[4];
#pragma unroll
    for (int rr = 0; rr < 4; rr++) {
      alpha[rr] = __builtin_exp2f((m_i[rr] - mnew[rr]) * cf);
      m_i[rr] = mnew[rr];
      rs[rr] = 0.0f;
    }
#pragma unroll
    for (int nb = 0; nb < 4; nb++)
#pragma unroll
      for (int rr = 0; rr < 4; rr++) {
        p[nb][rr] = __builtin_exp2f((s[nb][rr] - mnew[rr]) * cf);
        rs[rr] += p[nb][rr];
      }
#pragma unroll
    for (int off = 1; off < 16; off <<= 1)
#pragma unroll
      for (int rr = 0; rr < 4; rr++) rs[rr] += __shfl_xor(rs[rr], off);
#pragma unroll
    for (int rr = 0; rr < 4; rr++) l_i[rr] = l_i[rr] * alpha[rr] + rs[rr];
#pragma unroll
    for (int nb2 = 0; nb2 < 8; nb2++)
#pragma unroll
      for (int rr = 0; rr < 4; rr++) o[nb2][rr] *= alpha[rr];

    // P: C-layout -> LDS -> A-layout (per-wave slice; same-wave LDS in-order)
#pragma unroll
    for (int nb = 0; nb < 4; nb++)
#pragma unroll
      for (int rr = 0; rr < 4; rr++)
        Ps[w][quad * 4 + rr][nb * 16 + col] = f2bf(p[nb][rr]);

    bf16x8 pa0 = *(const bf16x8*)&Ps[w][col][quad * 8];
    bf16x8 pa1 = *(const bf16x8*)&Ps[w][col][quad * 8 + 32];
#pragma unroll
    for (int nb2 = 0; nb2 < 8; nb2++) {
      bf16x8 vb0 = *(const bf16x8*)&Vt[nb2 * 16 + col][quad * 8];
      bf16x8 vb1 = *(const bf16x8*)&Vt[nb2 * 16 + col][quad * 8 + 32];
      o[nb2] = __builtin_amdgcn_mfma_f32_16x16x32_bf16(pa0, vb0, o[nb2], 0, 0, 0);
      o[nb2] = __builtin_amdgcn_mfma_f32_16x16x32_bf16(pa1, vb1, o[nb2], 0, 0, 0);
    }
  }

  float inv[4];
#pragma unroll
  for (int rr = 0; rr < 4; rr++) inv[rr] = 1.0f / l_i[rr];
#pragma unroll
  for (int nb2 = 0; nb2 < 8; nb2++)
#pragma unroll
    for (int rr = 0; rr < 4; rr++) {
      size_t off2 = (size_t)(b * 1024 + qt * 64 + w * 16 + quad * 4 + rr) * 4096 +
                    h * 128 + nb2 * 16 + col;
      Og[off2] = f2bf(o[nb2][rr] * inv[rr]);
    }
}

extern "C" void kernel_launch(void* const* d_in, const int* in_sizes, int n_in,
                              void* d_out, int out_size, void* d_ws, size_t ws_size,
                              hipStream_t stream) {
  const float* hs = (const float*)d_in[0];
  const float* wq = (const float*)d_in[1];
  const float* wk = (const float*)d_in[2];
  const float* wv = (const float*)d_in[3];
  const float* wo = (const float*)d_in[4];
  const int* pos = (const int*)d_in[6];
  float* out = (float*)d_out;

  char* ws = (char*)d_ws;
  const size_t MB = 1ull << 20;
  u16* hs_bf = (u16*)(ws + 0);         // 32 MB
  u16* wq_bf = (u16*)(ws + 32 * MB);   // 32 MB
  u16* wk_bf = (u16*)(ws + 64 * MB);   // 8 MB  (wk+wv contiguous -> [2048][4096])
  u16* wv_bf = (u16*)(ws + 72 * MB);   // 8 MB
  u16* Qb    = (u16*)(ws + 80 * MB);   // 32 MB
  u16* KVb   = (u16*)(ws + 112 * MB);  // 16 MB  [4096][2048]: cols 0..1023=K, 1024..2047=V
  u16* wo_bf = hs_bf;                  // reuse after QKV GEMMs
  u16* AOb   = wq_bf;                  // reuse after q-proj GEMM

  // converts
  cvt_kernel<<<16384, 256, 0, stream>>>(hs, hs_bf, 4194304);
  cvt_kernel<<<16384, 256, 0, stream>>>(wq, wq_bf, 4194304);
  cvt_kernel<<<4096, 256, 0, stream>>>(wk, wk_bf, 1048576);
  cvt_kernel<<<4096, 256, 0, stream>>>(wv, wv_bf, 1048576);

  // projections
  gemm_bt<1><<<dim3(32, 32), 256, 0, stream>>>(hs_bf, wq_bf, Qb, 4096, 4096, 4096);
  gemm_bt<1><<<dim3(16, 32), 256, 0, stream>>>(hs_bf, wk_bf, KVb, 4096, 2048, 4096);

  // RoPE on Q and K
  rope_kernel<<<32768, 256, 0, stream>>>(Qb, pos, 5, 4096);
  rope_kernel<<<8192, 256, 0, stream>>>(KVb, pos, 3, 2048);

  // convert wo (reuses hs_bf slot; hs no longer needed)
  cvt_kernel<<<16384, 256, 0, stream>>>(wo, wo_bf, 4194304);

  // attention (K at KVb col 0, V at col 1024; row stride 2048)
  attn_kernel<<<dim3(16, 32, 4), 256, 0, stream>>>(Qb, KVb, KVb + 1024, AOb);

  // output projection -> fp32 d_out
  gemm_bt<0><<<dim3(32, 32), 256, 0, stream>>>(AOb, wo_bf, out, 4096, 4096, 4096);
}

// Round 2
// 1008.064 us; speedup vs baseline: 1.0022x; 1.0022x over previous
//
#include <hip/hip_runtime.h>

typedef unsigned short u16;
typedef __bf16 bf16x8 __attribute__((ext_vector_type(8)));
typedef float f32x4 __attribute__((ext_vector_type(4)));

__device__ __forceinline__ u16 f2bf(float f) {
  unsigned int u = __float_as_uint(f);
  u += 0x7fffu + ((u >> 16) & 1u);
  return (u16)(u >> 16);
}
__device__ __forceinline__ float bf2f(u16 v) {
  return __uint_as_float(((unsigned int)v) << 16);
}

// async global->LDS, 16B per lane. LDS dest must be wave-uniform base; HW adds lane*16.
__device__ __forceinline__ void gl_lds16(const u16* g, u16* l) {
  auto* lp = reinterpret_cast<__attribute__((address_space(3))) unsigned int*>(
      reinterpret_cast<uintptr_t>(l));
  auto* gp = reinterpret_cast<const __attribute__((address_space(1))) unsigned int*>(
      reinterpret_cast<uintptr_t>(g));
  __builtin_amdgcn_global_load_lds(gp, lp, 16, 0, 0);
}

// ---------------- fp32 -> bf16 convert ----------------
__global__ __launch_bounds__(256) void cvt_kernel(const float* __restrict__ in,
                                                  u16* __restrict__ out, int n4) {
  int i = blockIdx.x * 256 + threadIdx.x;
  if (i >= n4) return;
  float4 v = ((const float4*)in)[i];
  ushort4 o;
  o.x = f2bf(v.x); o.y = f2bf(v.y); o.z = f2bf(v.z); o.w = f2bf(v.w);
  ((ushort4*)out)[i] = o;
}

// ---------------- bf16 GEMM, C[m][n] = sum_k A[m][k] * B[n][k] ----------------
// 128x128 tile, BK=32, 256 threads (4 waves, 2x2 wave grid, 64x64 per wave).
template <int OUT_BF16>
__global__ __launch_bounds__(256) void gemm_bt(const u16* __restrict__ A,
                                               const u16* __restrict__ B,
                                               void* __restrict__ Cv, int M, int N, int K) {
  __shared__ u16 As[128 * 32];
  __shared__ u16 Bs[128 * 32];
  const int t = threadIdx.x;
  const int lane = t & 63, w = t >> 6;
  const int col = lane & 15, quad = lane >> 4;
  const int m0 = blockIdx.y * 128, n0 = blockIdx.x * 128;

  f32x4 acc[4][4] = {};

  const int r4 = t >> 2;          // 0..63
  const int c8 = (t & 3) * 8;     // k chunk within BK=32
  const u16* gA0 = A + (size_t)(m0 + r4) * K + c8;
  const u16* gA1 = A + (size_t)(m0 + 64 + r4) * K + c8;
  const u16* gB0 = B + (size_t)(n0 + r4) * K + c8;
  const u16* gB1 = B + (size_t)(n0 + 64 + r4) * K + c8;
  u16* lA0 = As + w * 512;        // wave-uniform LDS bases
  u16* lA1 = As + 2048 + w * 512;
  u16* lB0 = Bs + w * 512;
  u16* lB1 = Bs + 2048 + w * 512;

  const int mr = (w & 1) * 64, nr = (w >> 1) * 64;

  for (int k0 = 0; k0 < K; k0 += 32) {
    __syncthreads();
    gl_lds16(gA0 + k0, lA0);
    gl_lds16(gA1 + k0, lA1);
    gl_lds16(gB0 + k0, lB0);
    gl_lds16(gB1 + k0, lB1);
    __syncthreads();  // compiler drains vmcnt before s_barrier

    bf16x8 a[4], b[4];
#pragma unroll
    for (int i = 0; i < 4; i++)
      a[i] = *(const bf16x8*)&As[(mr + i * 16 + col) * 32 + quad * 8];
#pragma unroll
    for (int i = 0; i < 4; i++)
      b[i] = *(const bf16x8*)&Bs[(nr + i * 16 + col) * 32 + quad * 8];
#pragma unroll
    for (int i = 0; i < 4; i++)
#pragma unroll
      for (int j = 0; j < 4; j++)
        acc[i][j] = __builtin_amdgcn_mfma_f32_16x16x32_bf16(a[i], b[j], acc[i][j], 0, 0, 0);
  }

  // C/D layout: col = lane&15, row = quad*4 + reg
#pragma unroll
  for (int i = 0; i < 4; i++) {
#pragma unroll
    for (int j = 0; j < 4; j++) {
      int mb = m0 + mr + i * 16 + quad * 4;
      int n = n0 + nr + j * 16 + col;
#pragma unroll
      for (int r = 0; r < 4; r++) {
        float v = acc[i][j][r];
        if constexpr (OUT_BF16)
          ((u16*)Cv)[(size_t)(mb + r) * N + n] = f2bf(v);
        else
          ((float*)Cv)[(size_t)(mb + r) * N + n] = v;
      }
    }
  }
}

// ---------------- Llama-3.1 RoPE (rotate-half, non-interleaved) ----------------
__global__ __launch_bounds__(256) void rope_kernel(u16* __restrict__ X,
                                                   const int* __restrict__ pos_ids,
                                                   int log2H, int row_stride) {
  int tid = blockIdx.x * 256 + threadIdx.x;
  int i = tid & 63;
  int rest = tid >> 6;
  int h = rest & ((1 << log2H) - 1);
  int token = rest >> log2H;
  float pos = (float)pos_ids[token];
  // freq = 500000^(-i/64); log2(500000) = 18.93156856932417
  float fr = __builtin_exp2f(-(float)i * (18.93156856932417f / 64.0f));
  float wl = 6.283185307179586f / fr;
  float f2;
  if (wl < 2048.0f) f2 = fr;
  else if (wl > 8192.0f) f2 = fr * 0.125f;
  else {
    float sm = (8192.0f / wl - 1.0f) * (1.0f / 3.0f);
    f2 = (1.0f - sm) * fr * 0.125f + sm * fr;
  }
  float ang = pos * f2;
  float ss = sinf(ang), cc = cosf(ang);
  size_t base = (size_t)token * row_stride + (size_t)h * 128 + i;
  float x1 = bf2f(X[base]), x2 = bf2f(X[base + 64]);
  X[base] = f2bf(x1 * cc - x2 * ss);
  X[base + 64] = f2bf(x2 * cc + x1 * ss);
}

// ---------------- causal GQA flash attention v2 ----------------
// grid (16, 32, 4) = (qt rev, h, b), 256 threads. BM=BN=64; wave w owns Q rows [w*16,w*16+16).
// K staged in [key][d] layout, V^T staged in [d][key] layout, both via global_load_lds
// with XOR-swizzled 16B groups so all ds_read_b128 fragment reads are conflict-free.
__global__ __launch_bounds__(256) void attn_kernel(const u16* __restrict__ Qg,
                                                   const u16* __restrict__ Kg,
                                                   const u16* __restrict__ VTg,
                                                   u16* __restrict__ Og) {
  const int qt = 15 - blockIdx.x;  // long blocks dispatch first (load balance)
  const int h = blockIdx.y, b = blockIdx.z;
  const int kvh = h >> 2;  // GQA group of 4
  const int t = threadIdx.x, lane = t & 63, w = t >> 6;
  const int col = lane & 15, quad = lane >> 4;

  __shared__ u16 Ks[64 * 128];   // 16 KB, swizzled: [key][ (g ^ (key&15))*8 + e ]
  __shared__ u16 Vt[128 * 64];   // 16 KB, swizzled: [d]  [ (g ^ (d&7))*8 + e ]
  __shared__ u16 Ps[4][16][72];  // per-wave P strip, 9 KB

  // ---- stage Q (into Ks buffer) and pull A-fragments into registers ----
  {
    const u16* Qbase = Qg + (size_t)(b * 1024 + qt * 64) * 4096 + h * 128;
#pragma unroll
    for (int c = 0; c < 4; c++) {
      int ch = w * 4 + c;
      int row = ch * 4 + (lane >> 4);
      int g = (lane & 15) ^ (row & 15);
      gl_lds16(Qbase + (size_t)row * 4096 + g * 8, Ks + ch * 512);
    }
  }
  __syncthreads();
  bf16x8 qa[4];
#pragma unroll
  for (int kk = 0; kk < 4; kk++) {
    int row = w * 16 + col;
    qa[kk] = *(const bf16x8*)&Ks[row * 128 + (((quad + 4 * kk) ^ col) << 3)];
  }

  f32x4 o[8] = {};
  float m_i[4] = {-3.0e38f, -3.0e38f, -3.0e38f, -3.0e38f};
  float l_i[4] = {};

  const float cf = 0.08838834764831845f * 1.4426950408889634f;  // scale * log2(e)
  const int qrow0 = qt * 64 + w * 16 + quad * 4;

  const u16* Kbase = Kg + (size_t)(b * 1024) * 1024 + kvh * 128;
  const u16* Vbase = VTg + (size_t)(kvh * 128) * 4096 + b * 1024;

  for (int j = 0; j <= qt; j++) {
    __syncthreads();  // everyone done reading previous tile (and Q regs at j=0)
#pragma unroll
    for (int c = 0; c < 4; c++) {
      int ch = w * 4 + c;
      // K chunk: 4 rows (keys) of 128B
      int krow = ch * 4 + (lane >> 4);
      int kg = (lane & 15) ^ (krow & 15);
      gl_lds16(Kbase + (size_t)(j * 64 + krow) * 1024 + kg * 8, Ks + ch * 512);
      // V^T chunk: 8 rows (d) of 64B segments
      int vrow = ch * 8 + (lane >> 3);
      int vg = (lane & 7) ^ (vrow & 7);
      gl_lds16(Vbase + (size_t)vrow * 4096 + j * 64 + vg * 8, Vt + ch * 512);
    }
    __syncthreads();  // drains vmcnt before barrier

    // S = Q K^T  (rows=q via A, cols=key via B)
    f32x4 s[4] = {};
#pragma unroll
    for (int nb = 0; nb < 4; nb++) {
      int key = nb * 16 + col;
#pragma unroll
      for (int kk = 0; kk < 4; kk++) {
        bf16x8 kb2 = *(const bf16x8*)&Ks[key * 128 + (((quad + 4 * kk) ^ col) << 3)];
        s[nb] = __builtin_amdgcn_mfma_f32_16x16x32_bf16(qa[kk], kb2, s[nb], 0, 0, 0);
      }
    }

    if (j == qt) {  // diagonal tile: causal mask
#pragma unroll
      for (int nb = 0; nb < 4; nb++)
#pragma unroll
        for (int rr = 0; rr < 4; rr++)
          if (j * 64 + nb * 16 + col > qrow0 + rr) s[nb][rr] = -3.0e38f;
    }

    // online softmax; rows live across the 16 lanes of each quad
    float mnew[4];
#pragma unroll
    for (int rr = 0; rr < 4; rr++) {
      mnew[rr] = m_i[rr];
#pragma unroll
      for (int nb = 0; nb < 4; nb++) mnew[rr] = fmaxf(mnew[rr], s[nb][rr]);
    }
#pragma unroll
    for (int off = 1; off < 16; off <<= 1)
#pragma unroll
      for (int rr = 0; rr < 4; rr++)
        mnew[rr] = fmaxf(mnew[rr], __shfl_xor(mnew[rr], off));

    float p[4][4], rs[4], alpha[4];
#pragma unroll
    for (int rr = 0; rr < 4; rr++) {
      alpha[rr] = __builtin_exp2f((m_i[rr] - mnew[rr]) * cf);
      m_i[rr] = mnew[rr];
      rs[rr] = 0.0f;
    }
#pragma unroll
    for (int nb = 0; nb < 4; nb++)
#pragma unroll
      for (int rr = 0; rr < 4; rr++) {
        p[nb][rr] = __builtin_exp2f((s[nb][rr] - mnew[rr]) * cf);
        rs[rr] += p[nb][rr];
      }
#pragma unroll
    for (int off = 1; off < 16; off <<= 1)
#pragma unroll
      for (int rr = 0; rr < 4; rr++) rs[rr] += __shfl_xor(rs[rr], off);
#pragma unroll
    for (int rr = 0; rr < 4; rr++) l_i[rr] = l_i[rr] * alpha[rr] + rs[rr];
#pragma unroll
    for (int nb2 = 0; nb2 < 8; nb2++)
#pragma unroll
      for (int rr = 0; rr < 4; rr++) o[nb2][rr] *= alpha[rr];

    // P: C-layout -> LDS -> A-layout (per-wave slice; same-wave LDS in-order)
#pragma unroll
    for (int nb = 0; nb < 4; nb++)
#pragma unroll
      for (int rr = 0; rr < 4; rr++)
        Ps[w][quad * 4 + rr][nb * 16 + col] = f2bf(p[nb][rr]);

    bf16x8 pa0 = *(const bf16x8*)&Ps[w][col][quad * 8];
    bf16x8 pa1 = *(const bf16x8*)&Ps[w][col][quad * 8 + 32];
#pragma unroll
    for (int nb2 = 0; nb2 < 8; nb2++) {
      int d = nb2 * 16 + col;
      bf16x8 vb0 = *(const bf16x8*)&Vt[d * 64 + ((quad ^ (col & 7)) << 3)];
      bf16x8 vb1 = *(const bf16x8*)&Vt[d * 64 + ((((quad + 4) & 7) ^ (col & 7)) << 3)];
      o[nb2] = __builtin_amdgcn_mfma_f32_16x16x32_bf16(pa0, vb0, o[nb2], 0, 0, 0);
      o[nb2] = __builtin_amdgcn_mfma_f32_16x16x32_bf16(pa1, vb1, o[nb2], 0, 0, 0);
    }
  }

  float inv[4];
#pragma unroll
  for (int rr = 0; rr < 4; rr++) inv[rr] = 1.0f / l_i[rr];
#pragma unroll
  for (int nb2 = 0; nb2 < 8; nb2++)
#pragma unroll
    for (int rr = 0; rr < 4; rr++) {
      size_t off2 = (size_t)(b * 1024 + qt * 64 + w * 16 + quad * 4 + rr) * 4096 +
                    h * 128 + nb2 * 16 + col;
      Og[off2] = f2bf(o[nb2][rr] * inv[rr]);
    }
}

extern "C" void kernel_launch(void* const* d_in, const int* in_sizes, int n_in,
                              void* d_out, int out_size, void* d_ws, size_t ws_size,
                              hipStream_t stream) {
  const float* hs = (const float*)d_in[0];
  const float* wq = (const float*)d_in[1];
  const float* wk = (const float*)d_in[2];
  const float* wv = (const float*)d_in[3];
  const float* wo = (const float*)d_in[4];
  const int* pos = (const int*)d_in[6];
  float* out = (float*)d_out;

  char* ws = (char*)d_ws;
  const size_t MB = 1ull << 20;
  u16* hs_bf = (u16*)(ws + 0);         // 32 MB
  u16* wq_bf = (u16*)(ws + 32 * MB);   // 32 MB
  u16* wk_bf = (u16*)(ws + 64 * MB);   // 8 MB
  u16* wv_bf = (u16*)(ws + 72 * MB);   // 8 MB
  u16* Qb    = (u16*)(ws + 80 * MB);   // 32 MB  [4096 tok][4096]
  u16* Kb    = (u16*)(ws + 112 * MB);  // 8 MB   [4096 tok][1024]
  u16* VTb   = (u16*)(ws + 120 * MB);  // 8 MB   [1024 d][4096 tok]  (V transposed)
  u16* wo_bf = hs_bf;                  // reuse after projection GEMMs
  u16* AOb   = wq_bf;                  // reuse after q-proj GEMM

  // converts
  cvt_kernel<<<16384, 256, 0, stream>>>(hs, hs_bf, 4194304);
  cvt_kernel<<<16384, 256, 0, stream>>>(wq, wq_bf, 4194304);
  cvt_kernel<<<4096, 256, 0, stream>>>(wk, wk_bf, 1048576);
  cvt_kernel<<<4096, 256, 0, stream>>>(wv, wv_bf, 1048576);

  // projections: Q [tok][4096], K [tok][1024], V^T [d][tok]
  gemm_bt<1><<<dim3(32, 32), 256, 0, stream>>>(hs_bf, wq_bf, Qb, 4096, 4096, 4096);
  gemm_bt<1><<<dim3(8, 32), 256, 0, stream>>>(hs_bf, wk_bf, Kb, 4096, 1024, 4096);
  gemm_bt<1><<<dim3(32, 8), 256, 0, stream>>>(wv_bf, hs_bf, VTb, 1024, 4096, 4096);

  // RoPE on Q and K (V needs none)
  rope_kernel<<<32768, 256, 0, stream>>>(Qb, pos, 5, 4096);
  rope_kernel<<<8192, 256, 0, stream>>>(Kb, pos, 3, 1024);

  // convert wo (reuses hs_bf slot; hs no longer needed)
  cvt_kernel<<<16384, 256, 0, stream>>>(wo, wo_bf, 4194304);

  // attention
  attn_kernel<<<dim3(16, 32, 4), 256, 0, stream>>>(Qb, Kb, VTb, AOb);

  // output projection -> fp32 d_out
  gemm_bt<0><<<dim3(32, 32), 256, 0, stream>>>(AOb, wo_bf, out, 4096, 4096, 4096);
}

// Round 3
// 912.067 us; speedup vs baseline: 1.1076x; 1.1053x over previous
//
#include <hip/hip_runtime.h>

typedef unsigned short u16;
typedef __bf16 bf16x8 __attribute__((ext_vector_type(8)));
typedef float f32x4 __attribute__((ext_vector_type(4)));

__device__ __forceinline__ u16 f2bf(float f) {
  unsigned int u = __float_as_uint(f);
  u += 0x7fffu + ((u >> 16) & 1u);
  return (u16)(u >> 16);
}
__device__ __forceinline__ float bf2f(u16 v) {
  return __uint_as_float(((unsigned int)v) << 16);
}

// async global->LDS, 16B per lane. LDS dest must be wave-uniform base; HW adds lane*16.
__device__ __forceinline__ void gl_lds16(const u16* g, u16* l) {
  auto* lp = reinterpret_cast<__attribute__((address_space(3))) unsigned int*>(
      reinterpret_cast<uintptr_t>(l));
  auto* gp = reinterpret_cast<const __attribute__((address_space(1))) unsigned int*>(
      reinterpret_cast<uintptr_t>(g));
  __builtin_amdgcn_global_load_lds(gp, lp, 16, 0, 0);
}

// ---------------- fp32 -> bf16 convert ----------------
__global__ __launch_bounds__(256) void cvt_kernel(const float* __restrict__ in,
                                                  u16* __restrict__ out, int n4) {
  int i = blockIdx.x * 256 + threadIdx.x;
  if (i >= n4) return;
  float4 v = ((const float4*)in)[i];
  ushort4 o;
  o.x = f2bf(v.x); o.y = f2bf(v.y); o.z = f2bf(v.z); o.w = f2bf(v.w);
  ((ushort4*)out)[i] = o;
}

// ---------------- bf16 GEMM, C[m][n] = sum_k A[m][k] * B[n][k] ----------------
// 128x128 tile, BK=32, 256 threads (4 waves, 2x2 wave grid, 64x64 per wave).
template <int OUT_BF16>
__global__ __launch_bounds__(256) void gemm_bt(const u16* __restrict__ A,
                                               const u16* __restrict__ B,
                                               void* __restrict__ Cv, int M, int N, int K) {
  __shared__ u16 As[128 * 32];
  __shared__ u16 Bs[128 * 32];
  const int t = threadIdx.x;
  const int lane = t & 63, w = t >> 6;
  const int col = lane & 15, quad = lane >> 4;
  const int m0 = blockIdx.y * 128, n0 = blockIdx.x * 128;

  f32x4 acc[4][4] = {};

  const int r4 = t >> 2;          // 0..63
  const int c8 = (t & 3) * 8;     // k chunk within BK=32
  const u16* gA0 = A + (size_t)(m0 + r4) * K + c8;
  const u16* gA1 = A + (size_t)(m0 + 64 + r4) * K + c8;
  const u16* gB0 = B + (size_t)(n0 + r4) * K + c8;
  const u16* gB1 = B + (size_t)(n0 + 64 + r4) * K + c8;
  u16* lA0 = As + w * 512;        // wave-uniform LDS bases
  u16* lA1 = As + 2048 + w * 512;
  u16* lB0 = Bs + w * 512;
  u16* lB1 = Bs + 2048 + w * 512;

  const int mr = (w & 1) * 64, nr = (w >> 1) * 64;

  for (int k0 = 0; k0 < K; k0 += 32) {
    __syncthreads();
    gl_lds16(gA0 + k0, lA0);
    gl_lds16(gA1 + k0, lA1);
    gl_lds16(gB0 + k0, lB0);
    gl_lds16(gB1 + k0, lB1);
    __syncthreads();  // compiler drains vmcnt before s_barrier

    bf16x8 a[4], b[4];
#pragma unroll
    for (int i = 0; i < 4; i++)
      a[i] = *(const bf16x8*)&As[(mr + i * 16 + col) * 32 + quad * 8];
#pragma unroll
    for (int i = 0; i < 4; i++)
      b[i] = *(const bf16x8*)&Bs[(nr + i * 16 + col) * 32 + quad * 8];
#pragma unroll
    for (int i = 0; i < 4; i++)
#pragma unroll
      for (int j = 0; j < 4; j++)
        acc[i][j] = __builtin_amdgcn_mfma_f32_16x16x32_bf16(a[i], b[j], acc[i][j], 0, 0, 0);
  }

  // C/D layout: col = lane&15, row = quad*4 + reg
#pragma unroll
  for (int i = 0; i < 4; i++) {
#pragma unroll
    for (int j = 0; j < 4; j++) {
      int mb = m0 + mr + i * 16 + quad * 4;
      int n = n0 + nr + j * 16 + col;
#pragma unroll
      for (int r = 0; r < 4; r++) {
        float v = acc[i][j][r];
        if constexpr (OUT_BF16)
          ((u16*)Cv)[(size_t)(mb + r) * N + n] = f2bf(v);
        else
          ((float*)Cv)[(size_t)(mb + r) * N + n] = v;
      }
    }
  }
}

// ---------------- 64x64-tiled u16 transpose: out[c][r] = in[r][c] ----------------
__global__ __launch_bounds__(256) void transpose_kernel(const u16* __restrict__ in,
                                                        u16* __restrict__ out,
                                                        int in_stride, int out_stride) {
  __shared__ u16 tile[64][72];
  const int t = threadIdx.x;
  const int bm = blockIdx.y;  // input row tile
  const int bn = blockIdx.x;  // input col tile
  const int r = t >> 3, c = (t & 7) * 8;
  const u16* src = in + (size_t)(bm * 64 + r) * in_stride + bn * 64 + c;
  *(uint4*)&tile[r][c] = *(const uint4*)src;
  *(uint4*)&tile[r + 32][c] = *(const uint4*)(src + (size_t)32 * in_stride);
  __syncthreads();
  u16 vals[8];
  u16* dst = out + (size_t)(bn * 64 + r) * out_stride + bm * 64 + c;
#pragma unroll
  for (int i = 0; i < 8; i++) vals[i] = tile[c + i][r];
  *(uint4*)dst = *(uint4*)vals;
#pragma unroll
  for (int i = 0; i < 8; i++) vals[i] = tile[c + i][r + 32];
  *(uint4*)(dst + (size_t)32 * out_stride) = *(uint4*)vals;
}

// ---------------- Llama-3.1 RoPE (rotate-half, non-interleaved) ----------------
__global__ __launch_bounds__(256) void rope_kernel(u16* __restrict__ X,
                                                   const int* __restrict__ pos_ids,
                                                   int log2H, int row_stride) {
  int tid = blockIdx.x * 256 + threadIdx.x;
  int i = tid & 63;
  int rest = tid >> 6;
  int h = rest & ((1 << log2H) - 1);
  int token = rest >> log2H;
  float pos = (float)pos_ids[token];
  // freq = 500000^(-i/64); log2(500000) = 18.93156856932417
  float fr = __builtin_exp2f(-(float)i * (18.93156856932417f / 64.0f));
  float wl = 6.283185307179586f / fr;
  float f2;
  if (wl < 2048.0f) f2 = fr;
  else if (wl > 8192.0f) f2 = fr * 0.125f;
  else {
    float sm = (8192.0f / wl - 1.0f) * (1.0f / 3.0f);
    f2 = (1.0f - sm) * fr * 0.125f + sm * fr;
  }
  float ang = pos * f2;
  float ss = sinf(ang), cc = cosf(ang);
  size_t base = (size_t)token * row_stride + (size_t)h * 128 + i;
  float x1 = bf2f(X[base]), x2 = bf2f(X[base + 64]);
  X[base] = f2bf(x1 * cc - x2 * ss);
  X[base + 64] = f2bf(x2 * cc + x1 * ss);
}

// ---------------- causal GQA flash attention ----------------
// grid (16, 32, 4) = (qt rev, h, b), 256 threads. BM=BN=64; wave w owns Q rows [w*16,w*16+16).
// K staged in [key][d] layout, V^T staged in [d][key] layout, both via global_load_lds
// with XOR-swizzled 16B groups so all ds_read_b128 fragment reads are conflict-free.
__global__ __launch_bounds__(256) void attn_kernel(const u16* __restrict__ Qg,
                                                   const u16* __restrict__ Kg,
                                                   const u16* __restrict__ VTg,
                                                   u16* __restrict__ Og,
                                                   int QS, int KS) {
  const int qt = 15 - blockIdx.x;  // long blocks dispatch first (load balance)
  const int h = blockIdx.y, b = blockIdx.z;
  const int kvh = h >> 2;  // GQA group of 4
  const int t = threadIdx.x, lane = t & 63, w = t >> 6;
  const int col = lane & 15, quad = lane >> 4;

  __shared__ u16 Ks[64 * 128];   // 16 KB, swizzled: [key][ (g ^ (key&15))*8 + e ]
  __shared__ u16 Vt[128 * 64];   // 16 KB, swizzled: [d]  [ (g ^ (d&7))*8 + e ]
  __shared__ u16 Ps[4][16][72];  // per-wave P strip, 9 KB

  // ---- stage Q (into Ks buffer) and pull A-fragments into registers ----
  {
    const u16* Qbase = Qg + (size_t)(b * 1024 + qt * 64) * QS + h * 128;
#pragma unroll
    for (int c = 0; c < 4; c++) {
      int ch = w * 4 + c;
      int row = ch * 4 + (lane >> 4);
      int g = (lane & 15) ^ (row & 15);
      gl_lds16(Qbase + (size_t)row * QS + g * 8, Ks + ch * 512);
    }
  }
  __syncthreads();
  bf16x8 qa[4];
#pragma unroll
  for (int kk = 0; kk < 4; kk++) {
    int row = w * 16 + col;
    qa[kk] = *(const bf16x8*)&Ks[row * 128 + (((quad + 4 * kk) ^ col) << 3)];
  }

  f32x4 o[8] = {};
  float m_i[4] = {-3.0e38f, -3.0e38f, -3.0e38f, -3.0e38f};
  float l_i[4] = {};

  const float cf = 0.08838834764831845f * 1.4426950408889634f;  // scale * log2(e)
  const int qrow0 = qt * 64 + w * 16 + quad * 4;

  const u16* Kbase = Kg + (size_t)(b * 1024) * KS + kvh * 128;
  const u16* Vbase = VTg + (size_t)(kvh * 128) * 4096 + b * 1024;

  for (int j = 0; j <= qt; j++) {
    __syncthreads();  // everyone done reading previous tile (and Q regs at j=0)
#pragma unroll
    for (int c = 0; c < 4; c++) {
      int ch = w * 4 + c;
      // K chunk: 4 rows (keys) of 128B
      int krow = ch * 4 + (lane >> 4);
      int kg = (lane & 15) ^ (krow & 15);
      gl_lds16(Kbase + (size_t)(j * 64 + krow) * KS + kg * 8, Ks + ch * 512);
      // V^T chunk: 8 rows (d) of 64B segments
      int vrow = ch * 8 + (lane >> 3);
      int vg = (lane & 7) ^ (vrow & 7);
      gl_lds16(Vbase + (size_t)vrow * 4096 + j * 64 + vg * 8, Vt + ch * 512);
    }
    __syncthreads();  // drains vmcnt before barrier

    // S = Q K^T  (rows=q via A, cols=key via B)
    f32x4 s[4] = {};
#pragma unroll
    for (int nb = 0; nb < 4; nb++) {
      int key = nb * 16 + col;
#pragma unroll
      for (int kk = 0; kk < 4; kk++) {
        bf16x8 kb2 = *(const bf16x8*)&Ks[key * 128 + (((quad + 4 * kk) ^ col) << 3)];
        s[nb] = __builtin_amdgcn_mfma_f32_16x16x32_bf16(qa[kk], kb2, s[nb], 0, 0, 0);
      }
    }

    if (j == qt) {  // diagonal tile: causal mask
#pragma unroll
      for (int nb = 0; nb < 4; nb++)
#pragma unroll
        for (int rr = 0; rr < 4; rr++)
          if (j * 64 + nb * 16 + col > qrow0 + rr) s[nb][rr] = -3.0e38f;
    }

    // online softmax; rows live across the 16 lanes of each quad
    float mnew[4];
#pragma unroll
    for (int rr = 0; rr < 4; rr++) {
      mnew[rr] = m_i[rr];
#pragma unroll
      for (int nb = 0; nb < 4; nb++) mnew[rr] = fmaxf(mnew[rr], s[nb][rr]);
    }
#pragma unroll
    for (int off = 1; off < 16; off <<= 1)
#pragma unroll
      for (int rr = 0; rr < 4; rr++)
        mnew[rr] = fmaxf(mnew[rr], __shfl_xor(mnew[rr], off));

    float p[4][4], rs[4], alpha[4];
#pragma unroll
    for (int rr = 0; rr < 4; rr++) {
      alpha[rr] = __builtin_exp2f((m_i[rr] - mnew[rr]) * cf);
      m_i[rr] = mnew[rr];
      rs[rr] = 0.0f;
    }
#pragma unroll
    for (int nb = 0; nb < 4; nb++)
#pragma unroll
      for (int rr = 0; rr < 4; rr++) {
        p[nb][rr] = __builtin_exp2f((s[nb][rr] - mnew[rr]) * cf);
        rs[rr] += p[nb][rr];
      }
#pragma unroll
    for (int off = 1; off < 16; off <<= 1)
#pragma unroll
      for (int rr = 0; rr < 4; rr++) rs[rr] += __shfl_xor(rs[rr], off);
#pragma unroll
    for (int rr = 0; rr < 4; rr++) l_i[rr] = l_i[rr] * alpha[rr] + rs[rr];
#pragma unroll
    for (int nb2 = 0; nb2 < 8; nb2++)
#pragma unroll
      for (int rr = 0; rr < 4; rr++) o[nb2][rr] *= alpha[rr];

    // P: C-layout -> LDS -> A-layout (per-wave slice; same-wave LDS in-order)
#pragma unroll
    for (int nb = 0; nb < 4; nb++)
#pragma unroll
      for (int rr = 0; rr < 4; rr++)
        Ps[w][quad * 4 + rr][nb * 16 + col] = f2bf(p[nb][rr]);

    bf16x8 pa0 = *(const bf16x8*)&Ps[w][col][quad * 8];
    bf16x8 pa1 = *(const bf16x8*)&Ps[w][col][quad * 8 + 32];
#pragma unroll
    for (int nb2 = 0; nb2 < 8; nb2++) {
      int d = nb2 * 16 + col;
      bf16x8 vb0 = *(const bf16x8*)&Vt[d * 64 + ((quad ^ (col & 7)) << 3)];
      bf16x8 vb1 = *(const bf16x8*)&Vt[d * 64 + ((((quad + 4) & 7) ^ (col & 7)) << 3)];
      o[nb2] = __builtin_amdgcn_mfma_f32_16x16x32_bf16(pa0, vb0, o[nb2], 0, 0, 0);
      o[nb2] = __builtin_amdgcn_mfma_f32_16x16x32_bf16(pa1, vb1, o[nb2], 0, 0, 0);
    }
  }

  float inv[4];
#pragma unroll
  for (int rr = 0; rr < 4; rr++) inv[rr] = 1.0f / l_i[rr];
#pragma unroll
  for (int nb2 = 0; nb2 < 8; nb2++)
#pragma unroll
    for (int rr = 0; rr < 4; rr++) {
      size_t off2 = (size_t)(b * 1024 + qt * 64 + w * 16 + quad * 4 + rr) * 4096 +
                    h * 128 + nb2 * 16 + col;
      Og[off2] = f2bf(o[nb2][rr] * inv[rr]);
    }
}

extern "C" void kernel_launch(void* const* d_in, const int* in_sizes, int n_in,
                              void* d_out, int out_size, void* d_ws, size_t ws_size,
                              hipStream_t stream) {
  const float* hs = (const float*)d_in[0];
  const float* wq = (const float*)d_in[1];
  const float* wk = (const float*)d_in[2];
  const float* wv = (const float*)d_in[3];
  const float* wo = (const float*)d_in[4];
  const int* pos = (const int*)d_in[6];
  float* out = (float*)d_out;

  char* ws = (char*)d_ws;
  const size_t MB = 1ull << 20;
  // Phase 1 layout:
  u16* hs_bf   = (u16*)(ws + 0);        // 32 MB [4096][4096]
  u16* wqkv_bf = (u16*)(ws + 32 * MB);  // 48 MB [6144][4096] (wq|wk|wv stacked)
  u16* QKV     = (u16*)(ws + 80 * MB);  // 48 MB [4096 tok][6144]: Q|K|V
  // Phase 2 layout (after QKV GEMM, hs_bf & wqkv_bf dead):
  u16* wo_bf = (u16*)(ws + 0);          // 32 MB
  u16* AOb   = (u16*)(ws + 32 * MB);    // 32 MB [4096][4096] attention out
  u16* VTb   = (u16*)(ws + 64 * MB);    // 8 MB  [1024 d][4096 tok]

  // converts: hs + stacked QKV weight
  cvt_kernel<<<16384, 256, 0, stream>>>(hs, hs_bf, 4194304);
  cvt_kernel<<<16384, 256, 0, stream>>>(wq, wqkv_bf, 4194304);
  cvt_kernel<<<4096, 256, 0, stream>>>(wk, wqkv_bf + 16777216, 1048576);
  cvt_kernel<<<4096, 256, 0, stream>>>(wv, wqkv_bf + 20971520, 1048576);

  // fused QKV projection: [4096][6144], grid 48x32 = 1536 blocks (6/CU)
  gemm_bt<1><<<dim3(48, 32), 256, 0, stream>>>(hs_bf, wqkv_bf, QKV, 4096, 6144, 4096);

  // RoPE on Q (cols 0..4095) and K (cols 4096..5119), in place, stride 6144
  rope_kernel<<<32768, 256, 0, stream>>>(QKV, pos, 5, 6144);
  rope_kernel<<<8192, 256, 0, stream>>>(QKV + 4096, pos, 3, 6144);

  // V^T: transpose QKV[:, 5120:6144] -> VTb [1024][4096]
  transpose_kernel<<<dim3(16, 64), 256, 0, stream>>>(QKV + 5120, VTb, 6144, 4096);

  // convert wo (into dead hs_bf slot)
  cvt_kernel<<<16384, 256, 0, stream>>>(wo, wo_bf, 4194304);

  // attention: Q stride 6144, K stride 6144, V^T [1024][4096]
  attn_kernel<<<dim3(16, 32, 4), 256, 0, stream>>>(QKV, QKV + 4096, VTb, AOb, 6144, 6144);

  // output projection -> fp32 d_out
  gemm_bt<0><<<dim3(32, 32), 256, 0, stream>>>(AOb, wo_bf, out, 4096, 4096, 4096);
}